// Round 4
// baseline (633.405 us; speedup 1.0000x reference)
//
#include <hip/hip_runtime.h>
#include <hip/hip_bf16.h>

#define Nn 4
#define CIN 2048
#define Hh 59
#define Ww 59
#define HW 3481
#define MID 512
#define MMpad 3584       // 3481 padded to mult of 64
#define SW 30
#define SP 900
#define PP 1024          // pixels padded
#define EPSF 1e-5f

typedef __hip_bfloat16 bf16;
typedef __attribute__((ext_vector_type(8))) short short8;
typedef __attribute__((ext_vector_type(4))) float floatx4;
typedef unsigned short u16;

__device__ __forceinline__ float b2f(u16 u) { return __uint_as_float(((unsigned)u) << 16); }
__device__ __forceinline__ u16 f2b(float f) {
    unsigned u = __float_as_uint(f);
    return (u16)((u + 0x7FFF + ((u >> 16) & 1)) >> 16);  // RNE
}

__device__ __forceinline__ float load_in(const void* p, long i, int isf32)
{
    return isf32 ? ((const float*)p)[i] : b2f(((const u16*)p)[i]);
}

// In-block dtype probe (same semantics as the old probe_k kernel).
// Must be called by ALL threads of the block before any divergent return.
__device__ __forceinline__ int block_probe_f32(const u16* __restrict__ x, int* cnt)
{
    const int tid = threadIdx.x;
    if (tid == 0) *cnt = 0;
    __syncthreads();
    int local = 0;
    for (int i = tid; i < 8192; i += 256) {
        u16 u = x[i];
        int e = (u >> 7) & 0xFF;
        if (u != 0 && (e < 90 || e > 160)) local++;
    }
    atomicAdd(cnt, local);
    __syncthreads();
    return *cnt > 256;
}

// ---------------- prep mega-kernel ----------------------------------------
// blockIdx.y segments:
//   0: subsample+transpose x -> xsT      (3840 blocks)
//   1: identity copy x -> out first half (1792 blocks)
//   2: weight convert (7 segs x 512)     (3584 blocks)
//   3: BN prep (5 segs x 8)              (40 blocks)
struct WArgs {
    const void* src[7];
    u16* dst[7];
    long n[7];
};
struct BArgs {
    const void* src[5];
    float* dst[5];
    int C[5];
    int sbN[5];
};

__global__ __launch_bounds__(256) void prep_all(const void* __restrict__ x,
                                                void* __restrict__ out,
                                                u16* __restrict__ xsT,
                                                WArgs wa, BArgs ba)
{
    __shared__ int cnt;
    __shared__ u16 ls[64][34];
    const int seg = blockIdx.y;
    const int bx = blockIdx.x;
    const int tid = threadIdx.x;

    // uniform early-exit for idle blocks (before any syncthreads)
    int need;
    if (seg == 0)      need = (bx < 3840);
    else if (seg == 1) need = (bx < 1792);
    else if (seg == 2) need = (bx < 3584);
    else               need = (bx < 40);
    if (!need) return;

    const int f = block_probe_f32((const u16*)x, &cnt);

    if (seg == 0) {
        // subsample + transpose: x[n][c][::2,::2] -> xsT[n][p][c]
        const int c0 = (bx & 31) * 64;
        const int rest = bx >> 5;          // 0..119
        const int a = rest % 30;
        const int n = rest / 30;
        for (int idx = tid; idx < 1920; idx += 256) {
            int ci = idx / 30, b = idx - 30 * (idx / 30);
            float v = load_in(x, ((long)n * CIN + c0 + ci) * HW + a * 118 + 2 * b, f);
            ls[ci][b] = f2b(v);
        }
        __syncthreads();
        for (int idx = tid; idx < 1920; idx += 256) {
            int b = idx >> 6, ci = idx & 63;
            xsT[((long)n * PP + a * 30 + b) * CIN + c0 + ci] = ls[ci][b];
        }
    } else if (seg == 1) {
        // identity copy: x -> out first CIN channels (uint4 granules)
        const long per = f ? 1782272L : 891136L;
        const long total = Nn * per;
        const uint4* src = (const uint4*)x;
        uint4* dst = (uint4*)out;
        long base = (long)bx * 4096 + tid;
        #pragma unroll
        for (int kk = 0; kk < 16; kk++) {
            long i = base + kk * 256;
            if (i < total) {
                long n = i / per, r = i - n * per;
                dst[n * 2 * per + r] = src[i];
            }
        }
    } else if (seg == 2) {
        // weight convert -> bf16 bits
        const int s = bx >> 9;
        const long n = wa.n[s];
        const u16* su = (const u16*)wa.src[s];
        const float* sf = (const float*)wa.src[s];
        u16* d = wa.dst[s];
        for (long i = (long)(bx & 511) * 256 + tid; i < n; i += 512L * 256) {
            d[i] = f ? f2b(sf[i]) : su[i];
        }
    } else {
        // BN prep
        const int s = bx >> 3;
        const int C = ba.C[s];
        const int c = (bx & 7) * 256 + tid;
        if (c < C) {
            const void* bnp = ba.src[s];
            float g = load_in(bnp, c, f);
            float b = load_in(bnp, C + c, f);
            float m = load_in(bnp, 2 * C + c, f);
            float v = load_in(bnp, 3 * C + c, f);
            float sc = g / sqrtf(v + EPSF);
            float* dst = ba.dst[s];
            dst[c] = sc;
            dst[ba.sbN[s] + c] = b - m * sc;
        }
    }
}

// ---------------- MFMA GEMM v5 --------------------------------------------
// C[M][N] = A[M][K] * B[N][K]^T, tile BM=BN=128, BK=64. Single-buffered
// 32 KB LDS, 2 barriers/K-step. 256 threads = 4 waves (2x2), each 64x64.
// XOR-swizzled global source + linear global_load_lds dest + matching read.
// bandM=1 (PSA score GEMM): each 128-row block computes only the column
// band [(29-amax)*59, (59-amin)*59) its rows' softmax windows can read.
// aux z-slices (z >= nzGemm): 64x64 transpose slices for the agg B operand.
__device__ __forceinline__ void gl2lds16(const void* g, void* l)
{
    __builtin_amdgcn_global_load_lds(
        (const __attribute__((address_space(1))) void*)g,
        (__attribute__((address_space(3))) void*)l, 16, 0, 0);
}

__global__ __launch_bounds__(256) void mfma_gemm(
    const u16* __restrict__ A, long sA, long sA2,
    const u16* __restrict__ B, long sB, long sB2,
    u16* __restrict__ C, long sC, long sC2, int zGrp, int nzGemm,
    int ldc, int K, int bandM,
    const float* __restrict__ sb, int sbN, long sbStride, int relu,
    const void* auxIn, void* auxOut)
{
    __shared__ __align__(16) u16 As[128 * 64];   // 16 KB
    __shared__ __align__(16) u16 Bs[128 * 64];   // 16 KB
    const int z = blockIdx.z;
    const int tid = threadIdx.x;

    if (z >= nzGemm) {
        // 64x64 transpose: in[sl][PP][MID] -> out[sl][MID][PP]
        const int sl = z - nzGemm;
        const int id = blockIdx.y * gridDim.x + blockIdx.x;   // needs 128
        if (id >= 128) return;
        u16 (*ls)[66] = (u16(*)[66])As;
        const u16* in = (const u16*)auxIn + (long)sl * (PP * MID);
        u16* out = (u16*)auxOut + (long)sl * (MID * PP);
        const int c0 = (id & 7) * 64;
        const int r0 = (id >> 3) * 64;
        const int t63 = tid & 63, t2 = tid >> 6;
        #pragma unroll
        for (int s = 0; s < 16; s++)
            ls[t2 + s * 4][t63] = in[(long)(r0 + t2 + s * 4) * MID + c0 + t63];
        __syncthreads();
        #pragma unroll
        for (int s = 0; s < 16; s++)
            out[(long)(c0 + t2 + s * 4) * PP + r0 + t63] = ls[t63][t2 + s * 4];
        return;
    }

    const int m_base = blockIdx.y * 128;
    int n_base;
    if (bandM) {
        const int pmin = m_base & 1023;
        int amin = pmin / 30; if (amin > 29) amin = 29;
        int amax = (pmin + 127) / 30; if (amax > 29) amax = 29;
        const int col_lo = (29 - amax) * 59;
        const int col_hi = (59 - amin) * 59;         // exclusive
        n_base = ((col_lo >> 7) + blockIdx.x) * 128;
        if (n_base >= col_hi) return;                // uniform exit
    } else {
        n_base = blockIdx.x * 128;
    }

    const int zi = z % zGrp, zg = z / zGrp;
    const int lane = tid & 63;
    const int w = tid >> 6;
    const u16* Az = A + (long)zi * sA + (long)zg * sA2;
    const u16* Bz = B + (long)zi * sB + (long)zg * sB2;
    u16* Cz = C + (long)zi * sC + (long)zg * sC2;
    const float* sbz = sb ? sb + (long)zg * sbStride : (const float*)0;

    const int quad = lane >> 4;
    const int l15 = lane & 15;
    const int wr = w >> 1, wc = w & 1;
    const int r8 = lane >> 3, c8 = lane & 7;
    const int swz = (c8 ^ r8) * 8;             // pre-swizzled k-chunk (u16)

    const long aRow = m_base + w * 32 + r8;    // + i*8
    const long bRow = n_base + w * 32 + r8;    // + j*8
    const int ldsOff = w * 2048 + lane * 8;    // wave-uniform + lane*16B

    floatx4 acc[4][4] = {};

    for (int k0 = 0; k0 < K; k0 += 64) {
        #pragma unroll
        for (int i = 0; i < 4; i++)
            gl2lds16(Az + (aRow + i * 8) * (long)K + k0 + swz,
                     &As[ldsOff + i * 512]);
        #pragma unroll
        for (int j = 0; j < 4; j++)
            gl2lds16(Bz + (bRow + j * 8) * (long)K + k0 + swz,
                     &Bs[ldsOff + j * 512]);
        __syncthreads();
        #pragma unroll
        for (int kk = 0; kk < 2; kk++) {
            const int sw = ((kk * 4 + quad) ^ (l15 & 7)) * 8;
            short8 af[4], bfv[4];
            #pragma unroll
            for (int t = 0; t < 4; t++)
                af[t] = *(const short8*)&As[(wr * 64 + t * 16 + l15) * 64 + sw];
            #pragma unroll
            for (int u = 0; u < 4; u++)
                bfv[u] = *(const short8*)&Bs[(wc * 64 + u * 16 + l15) * 64 + sw];
            #pragma unroll
            for (int t = 0; t < 4; t++)
                #pragma unroll
                for (int u = 0; u < 4; u++)
                    acc[t][u] = __builtin_amdgcn_mfma_f32_16x16x32_bf16(af[t], bfv[u], acc[t][u], 0, 0, 0);
        }
        __syncthreads();
    }

    #pragma unroll
    for (int u = 0; u < 4; u++) {
        int n = n_base + wc * 64 + u * 16 + l15;
        float scale = 1.f, bias = 0.f;
        if (sbz) { scale = sbz[n]; bias = sbz[sbN + n]; }
        #pragma unroll
        for (int t = 0; t < 4; t++) {
            int mrow = m_base + wr * 64 + t * 16 + quad * 4;
            #pragma unroll
            for (int r = 0; r < 4; r++) {
                float v = acc[t][u][r];
                v = v * scale + bias;
                if (relu) v = fmaxf(v, 0.f);
                Cz[(long)(mrow + r) * ldc + n] = f2b(v);
            }
        }
    }
}

// ---------------- gather + softmax: y_t[n][p][m3584] -> P_t[n][ab][ij] -----
// Grid x = 1024: blocks ab>=900 write zero rows (replaces the P memset);
// pad cols ij in [900,1024) written as zero by all blocks.
// dual=1: blockIdx.y encodes {branch(2) x batch(4)}; branch 0 = collect.
__global__ __launch_bounds__(256) void softmax_gather_k(const u16* __restrict__ y,
                                                        u16* __restrict__ P,
                                                        int collect, long yS2,
                                                        long pS2, int dual)
{
    const int ab = blockIdx.x;      // 0..1023
    int n;
    if (dual) {
        int br = blockIdx.y >> 2;
        n = blockIdx.y & 3;
        collect = (br == 0);
        y += (long)br * yS2;
        P += (long)br * pS2;
    } else {
        n = blockIdx.y;
    }
    const int t = threadIdx.x;
    u16* Prow = P + ((long)n * PP + ab) * PP;

    if (ab >= SP) {                 // pad rows -> exact zeros
        #pragma unroll
        for (int q = 0; q < 4; q++) Prow[t + q * 256] = 0;
        return;
    }

    const int a = ab / SW, b = ab - a * SW;
    __shared__ float red[4];

    float vals[4];
    float mx = -1e30f;
    #pragma unroll
    for (int q = 0; q < 4; q++) {
        int ij = t + q * 256;
        float v = -1e30f;
        if (ij < SP) {
            int i = ij / SW, j = ij - (ij / SW) * SW;
            long idx;
            if (collect) idx = ((long)n * PP + ab) * MMpad + (i - a + 29) * 59 + (j - b + 29);
            else         idx = ((long)n * PP + ij) * MMpad + (a - i + 29) * 59 + (b - j + 29);
            v = b2f(y[idx]);
        }
        vals[q] = v;
        mx = fmaxf(mx, v);
    }
    #pragma unroll
    for (int off = 32; off; off >>= 1) mx = fmaxf(mx, __shfl_xor(mx, off, 64));
    if ((t & 63) == 0) red[t >> 6] = mx;
    __syncthreads();
    mx = fmaxf(fmaxf(red[0], red[1]), fmaxf(red[2], red[3]));
    __syncthreads();

    float s = 0.f;
    #pragma unroll
    for (int q = 0; q < 4; q++) {
        if (vals[q] > -1e29f) { vals[q] = expf(vals[q] - mx); s += vals[q]; }
        else vals[q] = 0.f;
    }
    #pragma unroll
    for (int off = 32; off; off >>= 1) s += __shfl_xor(s, off, 64);
    if ((t & 63) == 0) red[t >> 6] = s;
    __syncthreads();
    s = red[0] + red[1] + red[2] + red[3];
    float inv = 1.f / s;
    #pragma unroll
    for (int q = 0; q < 4; q++) {
        int ij = t + q * 256;
        Prow[ij] = f2b(vals[q] * inv);   // vals==0 for pad cols -> writes 0
    }
}

// ---------------- 2x upsample from xp_t[n][p][c], write out 2nd half --------
__global__ __launch_bounds__(256) void upsample_k(const u16* __restrict__ xp,
                                                  void* __restrict__ out,
                                                  const void* __restrict__ xprobe)
{
    __shared__ int cnt;
    __shared__ u16 ls[2][30][66];
    const int f = block_probe_f32((const u16*)xprobe, &cnt);
    const int o0 = blockIdx.x * 64;
    const int y  = blockIdx.y;          // 0..58
    const int n  = blockIdx.z;
    const int tid = threadIdx.x;
    const int i = y >> 1;
    const int i1 = (i + 1 < 30) ? i + 1 : 29;
    const int c = tid & 63;
    for (int row = tid >> 6; row < 60; row += 4) {
        int r = row / 30, j = row - 30 * (row / 30);
        int pr = (r == 0) ? i : i1;
        ls[r][j][c] = xp[((long)n * PP + pr * 30 + j) * CIN + o0 + c];
    }
    __syncthreads();
    const int xcol = tid & 63;
    const int oi = tid >> 6;
    if (xcol < 59) {
        int j = xcol >> 1;
        bool xe = !(xcol & 1), ye = !(y & 1);
        for (int oo = oi; oo < 64; oo += 4) {
            float v00 = b2f(ls[0][j][oo]);
            float v;
            if (ye && xe)      v = v00;
            else if (ye)       v = 0.5f * (v00 + b2f(ls[0][j + 1][oo]));
            else if (xe)       v = 0.5f * (v00 + b2f(ls[1][j][oo]));
            else               v = 0.25f * (v00 + b2f(ls[0][j + 1][oo])
                                          + b2f(ls[1][j][oo]) + b2f(ls[1][j + 1][oo]));
            long oidx = ((long)n * (2 * CIN) + CIN + o0 + oo) * HW + (long)y * 59 + xcol;
            if (f) ((float*)out)[oidx] = v;
            else   ((u16*)out)[oidx] = f2b(v);
        }
    }
}

// ---------------- launch ----------------
extern "C" void kernel_launch(void* const* d_in, const int* in_sizes, int n_in,
                              void* d_out, int out_size, void* d_ws, size_t ws_size,
                              hipStream_t stream)
{
    const void* x    = d_in[0];
    const void* rw   = d_in[1];
    const void* rbn  = d_in[2];
    const void* a1w  = d_in[3];
    const void* abn  = d_in[4];
    const void* a2w  = d_in[5];
    const void* rpw  = d_in[6];
    const void* rpbn = d_in[7];
    const void* ap1w = d_in[8];
    const void* apbn = d_in[9];
    const void* ap2w = d_in[10];
    const void* pjw  = d_in[11];
    const void* pjbn = d_in[12];

    const long sMid = (long)PP * MID;      // 524288 u16
    const long sO   = (long)MID * PP;      // 524288 u16
    const long sPPl = (long)PP * PP;       // 1048576 u16
    const long sMM  = (long)PP * MMpad;    // 3670016 u16

    // big layout needs 2x y_t: guard on ws_size, fall back to serial branches
    const int bigWs = (ws_size >= 134251776UL) ? 1 : 0;

    char* W = (char*)d_ws;
    u16* rw_b    = (u16*)(W + 1024);          // 512x2048
    u16* rpw_b   = (u16*)(W + 2098176);       // 512x2048 (contiguous)
    u16* a1w_b   = (u16*)(W + 4195328);       // 512x512
    u16* ap1w_b  = (u16*)(W + 4719616);       // contiguous
    u16* a2w_b   = (u16*)(W + 5243904);       // 3584x512 (pad rows garbage)
    u16* ap2w_b  = (u16*)(W + 8913920);       // contiguous (+1835008 u16)
    u16* pjw_b   = (u16*)(W + 12583936);      // 2048x1024
    float* sbG1  = (float*)(W + 16778240);    // [s_c|b_c][s_d|b_d] 2048 f
    float* sbG2  = (float*)(W + 16786432);
    float* pj_sb = (float*)(W + 16794624);    // [s(2048)|b(2048)]
    u16* x_small_t = (u16*)(W + 16811264);    // 4x1024x2048 (reused: h1, xp_t)
    u16* xc_t      = (u16*)(W + 33588480);    // 4x1024x512
    u16* xc_o      = (u16*)(W + 41977088);    // 4x512x1024 (+xd_o contiguous)
    u16* y_t       = (u16*)(W + 50365696);    // 4x1024x3584 (x2 if bigWs)
    u16* Pc        = bigWs ? (u16*)(W + 109085952) : (u16*)(W + 79725824);
    u16* Pd        = Pc + 4 * sPPl;           // contiguous
    u16* cat_t     = Pd + 4 * sPPl;           // contiguous
    u16* h1        = x_small_t;               // 2 x [4096][512] after G1
    u16* xp_t      = x_small_t;               // [4096][2048] after agg

    WArgs wa;
    wa.src[0] = rw;   wa.dst[0] = rw_b;   wa.n[0] = 1048576;
    wa.src[1] = rpw;  wa.dst[1] = rpw_b;  wa.n[1] = 1048576;
    wa.src[2] = a1w;  wa.dst[2] = a1w_b;  wa.n[2] = 262144;
    wa.src[3] = ap1w; wa.dst[3] = ap1w_b; wa.n[3] = 262144;
    wa.src[4] = a2w;  wa.dst[4] = a2w_b;  wa.n[4] = 1782272;
    wa.src[5] = ap2w; wa.dst[5] = ap2w_b; wa.n[5] = 1782272;
    wa.src[6] = pjw;  wa.dst[6] = pjw_b;  wa.n[6] = 2097152;

    BArgs ba;
    ba.src[0] = rbn;  ba.dst[0] = sbG1;        ba.C[0] = 512;  ba.sbN[0] = 512;
    ba.src[1] = rpbn; ba.dst[1] = sbG1 + 1024; ba.C[1] = 512;  ba.sbN[1] = 512;
    ba.src[2] = abn;  ba.dst[2] = sbG2;        ba.C[2] = 512;  ba.sbN[2] = 512;
    ba.src[3] = apbn; ba.dst[3] = sbG2 + 1024; ba.C[3] = 512;  ba.sbN[3] = 512;
    ba.src[4] = pjbn; ba.dst[4] = pj_sb;       ba.C[4] = 2048; ba.sbN[4] = 2048;

    // 1) prep: probe + subsampleT + identity copy + weight cvt + BN prep
    hipLaunchKernelGGL(prep_all, dim3(3840, 4), dim3(256), 0, stream,
                       x, d_out, x_small_t, wa, ba);

    // 2) G1: [xc_t|xd_t] = relu(bn(x_small @ {rw,rpw}^T)); z=branch
    hipLaunchKernelGGL(mfma_gemm, dim3(4, 32, 2), dim3(256), 0, stream,
                       x_small_t, 0L, 0L,
                       rw_b, 0L, 1048576L,
                       xc_t, 0L, 4 * sMid, 1, 2,
                       MID, CIN, 0, sbG1, 512, 1024L, 1,
                       nullptr, nullptr);
    // 3) G2 + fused transposes: z 0..1 GEMM, z 2..9 transpose (8 x 128 blk)
    hipLaunchKernelGGL(mfma_gemm, dim3(4, 32, 10), dim3(256), 0, stream,
                       xc_t, 0L, 4 * sMid,
                       a1w_b, 0L, 262144L,
                       h1, 0L, 4 * sMid, 1, 2,
                       MID, MID, 0, sbG2, 512, 1024L, 1,
                       xc_t, xc_o);

    if (bigWs) {
        // 4) G3 both branches, band-trimmed (gridx 18 covers any band)
        hipLaunchKernelGGL(mfma_gemm, dim3(18, 32, 2), dim3(256), 0, stream,
                           h1, 0L, 4 * sMid,
                           a2w_b, 0L, 1835008L,
                           y_t, 0L, 4 * sMM, 1, 2,
                           MMpad, MID, 1, (const float*)nullptr, 0, 0L, 0,
                           nullptr, nullptr);
        // 5) softmax both branches; self-zeroes P pad rows/cols
        hipLaunchKernelGGL(softmax_gather_k, dim3(1024, 8), dim3(256), 0, stream,
                           y_t, Pc, 0, 4 * sMM, 4 * sPPl, 1);
    } else {
        hipLaunchKernelGGL(mfma_gemm, dim3(18, 32, 1), dim3(256), 0, stream,
                           h1, 0L, 0L, a2w_b, 0L, 0L, y_t, 0L, 0L, 1, 1,
                           MMpad, MID, 1, (const float*)nullptr, 0, 0L, 0,
                           nullptr, nullptr);
        hipLaunchKernelGGL(softmax_gather_k, dim3(1024, 4), dim3(256), 0, stream,
                           y_t, Pc, 1, 0L, 0L, 0);
        hipLaunchKernelGGL(mfma_gemm, dim3(18, 32, 1), dim3(256), 0, stream,
                           h1 + 4 * sMid, 0L, 0L, ap2w_b, 0L, 0L, y_t, 0L, 0L, 1, 1,
                           MMpad, MID, 1, (const float*)nullptr, 0, 0L, 0,
                           nullptr, nullptr);
        hipLaunchKernelGGL(softmax_gather_k, dim3(1024, 4), dim3(256), 0, stream,
                           y_t, Pd, 0, 0L, 0L, 0);
    }

    // 6) agg: cat_t[:, :512] = Pc @ xc_o^T ; cat_t[:, 512:] = Pd @ xd_o^T
    hipLaunchKernelGGL(mfma_gemm, dim3(4, 8, 8), dim3(256), 0, stream,
                       Pc, sPPl, 4 * sPPl,
                       xc_o, sO, 4 * sO,
                       cat_t, sPPl, 512L, 4, 8,
                       PP, PP, 0, (const float*)nullptr, 0, 0L, 0,
                       nullptr, nullptr);
    // 7) projection: xp_t = relu(bn(cat_t @ pjw^T)); M=4096
    hipLaunchKernelGGL(mfma_gemm, dim3(16, 32, 1), dim3(256), 0, stream,
                       cat_t, 0L, 0L,
                       pjw_b, 0L, 0L,
                       xp_t, 0L, 0L, 1, 1,
                       CIN, PP, 0, pj_sb, 2048, 0L, 1,
                       nullptr, nullptr);
    // 8) upsample (re-probes dtype in-block)
    hipLaunchKernelGGL(upsample_k, dim3(32, 59, 4), dim3(256), 0, stream,
                       xp_t, d_out, x);
}

// Round 6
// 566.696 us; speedup vs baseline: 1.1177x; 1.1177x over previous
//
#include <hip/hip_runtime.h>
#include <hip/hip_bf16.h>

#define Nn 4
#define CIN 2048
#define Hh 59
#define Ww 59
#define HW 3481
#define MID 512
#define MMpad 3584       // 3481 padded to mult of 64
#define SW 30
#define SP 900
#define PP 1024          // pixels padded
#define EPSF 1e-5f

typedef __hip_bfloat16 bf16;
typedef __attribute__((ext_vector_type(8))) short short8;
typedef __attribute__((ext_vector_type(4))) float floatx4;
typedef unsigned short u16;

__device__ __forceinline__ float b2f(u16 u) { return __uint_as_float(((unsigned)u) << 16); }
__device__ __forceinline__ u16 f2b(float f) {
    unsigned u = __float_as_uint(f);
    return (u16)((u + 0x7FFF + ((u >> 16) & 1)) >> 16);  // RNE
}

__device__ __forceinline__ float load_in(const void* p, long i, int isf32)
{
    return isf32 ? ((const float*)p)[i] : b2f(((const u16*)p)[i]);
}

// ---------------- dtype probe: bf16 vs fp32 (single tiny kernel) ----------
__global__ void probe_k(const u16* __restrict__ x, int* __restrict__ flag)
{
    __shared__ int cnt;
    if (threadIdx.x == 0) cnt = 0;
    __syncthreads();
    int local = 0;
    for (int i = threadIdx.x; i < 8192; i += 256) {
        u16 u = x[i];
        int e = (u >> 7) & 0xFF;
        if (u != 0 && (e < 90 || e > 160)) local++;
    }
    atomicAdd(&cnt, local);
    __syncthreads();
    if (threadIdx.x == 0) *flag = (cnt > 256) ? 1 : 0;   // 1 = fp32
}

// ---------------- prep mega-kernel (flag-based, tight 1-D grid) -----------
// block ranges: [0,3840) subsample+T, [3840,5632) identity copy,
//               [5632,9216) weight cvt, [9216,9256) BN prep
struct WArgs {
    const void* src[7];
    u16* dst[7];
    long n[7];
};
struct BArgs {
    const void* src[5];
    float* dst[5];
    int C[5];
    int sbN[5];
};

__global__ __launch_bounds__(256) void prep_all(const void* __restrict__ x,
                                                void* __restrict__ out,
                                                u16* __restrict__ xsT,
                                                WArgs wa, BArgs ba,
                                                const int* __restrict__ flag)
{
    __shared__ u16 ls[64][34];
    const int bx = blockIdx.x;
    const int tid = threadIdx.x;
    const int f = *flag;

    if (bx < 3840) {
        // subsample + transpose: x[n][c][::2,::2] -> xsT[n][p][c]
        const int c0 = (bx & 31) * 64;
        const int rest = bx >> 5;          // 0..119
        const int a = rest % 30;
        const int n = rest / 30;
        for (int idx = tid; idx < 1920; idx += 256) {
            int ci = idx / 30, b = idx - 30 * (idx / 30);
            float v = load_in(x, ((long)n * CIN + c0 + ci) * HW + a * 118 + 2 * b, f);
            ls[ci][b] = f2b(v);
        }
        __syncthreads();
        for (int idx = tid; idx < 1920; idx += 256) {
            int b = idx >> 6, ci = idx & 63;
            xsT[((long)n * PP + a * 30 + b) * CIN + c0 + ci] = ls[ci][b];
        }
    } else if (bx < 5632) {
        // identity copy: x -> out first CIN channels (uint4 granules)
        const int cb = bx - 3840;          // 0..1791
        const long per = f ? 1782272L : 891136L;
        const long total = Nn * per;
        const uint4* src = (const uint4*)x;
        uint4* dst = (uint4*)out;
        long base = (long)cb * 4096 + tid;
        #pragma unroll
        for (int kk = 0; kk < 16; kk++) {
            long i = base + kk * 256;
            if (i < total) {
                long n = i / per, r = i - n * per;
                dst[n * 2 * per + r] = src[i];
            }
        }
    } else if (bx < 9216) {
        // weight convert -> bf16 bits
        const int wb = bx - 5632;
        const int s = wb >> 9;
        const long n = wa.n[s];
        const u16* su = (const u16*)wa.src[s];
        const float* sf = (const float*)wa.src[s];
        u16* d = wa.dst[s];
        for (long i = (long)(wb & 511) * 256 + tid; i < n; i += 512L * 256) {
            d[i] = f ? f2b(sf[i]) : su[i];
        }
    } else {
        // BN prep
        const int bb = bx - 9216;
        const int s = bb >> 3;
        const int C = ba.C[s];
        const int c = (bb & 7) * 256 + tid;
        if (c < C) {
            const void* bnp = ba.src[s];
            float g = load_in(bnp, c, f);
            float b = load_in(bnp, C + c, f);
            float m = load_in(bnp, 2 * C + c, f);
            float v = load_in(bnp, 3 * C + c, f);
            float sc = g / sqrtf(v + EPSF);
            float* dst = ba.dst[s];
            dst[c] = sc;
            dst[ba.sbN[s] + c] = b - m * sc;
        }
    }
}

// ---------------- MFMA GEMM v6 --------------------------------------------
// C[M][N] = A[M][K] * B[N][K]^T, tile BM=BN=128, BK=64. Single-buffered
// 32 KB LDS, 2 barriers/K-step. 256 threads = 4 waves (2x2), each 64x64.
// NOTE: A and B are addressed with LEADING DIM == K (row stride = K u16).
// Callers must pass K equal to the true row stride (R5 bug: agg K-trim 960
// with stride-1024 buffers -> skewed reads, absmax 0.98).
// XOR-swizzled global source + linear global_load_lds dest + matching read.
// XCD-chunked block swizzle (T1/m157): linear block id -> (xcd = id%8 owns a
// contiguous m-range, n fastest) so A row-panels and B become XCD-L2-resident
// instead of re-fetched from L3 per tile. Requires gx*gy % 8 == 0 (all call
// sites: 128/128/576/32/512).
// bandM=1 (PSA score GEMM): compute only the column band the softmax reads.
// aux z-slices (z >= nzGemm): 64x64 transpose slices for the agg B operand.
__device__ __forceinline__ void gl2lds16(const void* g, void* l)
{
    __builtin_amdgcn_global_load_lds(
        (const __attribute__((address_space(1))) void*)g,
        (__attribute__((address_space(3))) void*)l, 16, 0, 0);
}

__global__ __launch_bounds__(256) void mfma_gemm(
    const u16* __restrict__ A, long sA, long sA2,
    const u16* __restrict__ B, long sB, long sB2,
    u16* __restrict__ C, long sC, long sC2, int zGrp, int nzGemm,
    int ldc, int K, int bandM,
    const float* __restrict__ sb, int sbN, long sbStride, int relu,
    const void* auxIn, void* auxOut)
{
    __shared__ __align__(16) u16 As[128 * 64];   // 16 KB
    __shared__ __align__(16) u16 Bs[128 * 64];   // 16 KB
    const int z = blockIdx.z;
    const int tid = threadIdx.x;

    if (z >= nzGemm) {
        // 64x64 transpose: in[sl][PP][MID] -> out[sl][MID][PP]
        const int sl = z - nzGemm;
        const int id = blockIdx.y * gridDim.x + blockIdx.x;
        if (id >= 128) return;
        u16 (*ls)[66] = (u16(*)[66])As;
        const u16* in = (const u16*)auxIn + (long)sl * (PP * MID);
        u16* out = (u16*)auxOut + (long)sl * (MID * PP);
        const int c0 = (id & 7) * 64;
        const int r0 = (id >> 3) * 64;
        const int t63 = tid & 63, t2 = tid >> 6;
        #pragma unroll
        for (int s = 0; s < 16; s++)
            ls[t2 + s * 4][t63] = in[(long)(r0 + t2 + s * 4) * MID + c0 + t63];
        __syncthreads();
        #pragma unroll
        for (int s = 0; s < 16; s++)
            out[(long)(c0 + t2 + s * 4) * PP + r0 + t63] = ls[t63][t2 + s * 4];
        return;
    }

    // XCD-chunked swizzle: id%8 == XCD (grid total %8==0); give each XCD a
    // contiguous chunk of (m,n) tiles with n varying fastest.
    const int gx = gridDim.x;
    const int tot = gx * gridDim.y;
    int id = blockIdx.y * gx + blockIdx.x;
    id = (id & 7) * (tot >> 3) + (id >> 3);
    const int m_idx = id / gx;
    const int n_idx = id - m_idx * gx;

    const int m_base = m_idx * 128;
    int n_base;
    if (bandM) {
        const int pmin = m_base & 1023;
        int amin = pmin / 30; if (amin > 29) amin = 29;
        int amax = (pmin + 127) / 30; if (amax > 29) amax = 29;
        const int col_lo = (29 - amax) * 59;
        const int col_hi = (59 - amin) * 59;         // exclusive
        n_base = ((col_lo >> 7) + n_idx) * 128;
        if (n_base >= col_hi) return;                // uniform exit
    } else {
        n_base = n_idx * 128;
    }

    const int zi = z % zGrp, zg = z / zGrp;
    const int lane = tid & 63;
    const int w = tid >> 6;
    const u16* Az = A + (long)zi * sA + (long)zg * sA2;
    const u16* Bz = B + (long)zi * sB + (long)zg * sB2;
    u16* Cz = C + (long)zi * sC + (long)zg * sC2;
    const float* sbz = sb ? sb + (long)zg * sbStride : (const float*)0;

    const int quad = lane >> 4;
    const int l15 = lane & 15;
    const int wr = w >> 1, wc = w & 1;
    const int r8 = lane >> 3, c8 = lane & 7;
    const int swz = (c8 ^ r8) * 8;             // pre-swizzled k-chunk (u16)

    const long aRow = m_base + w * 32 + r8;    // + i*8
    const long bRow = n_base + w * 32 + r8;    // + j*8
    const int ldsOff = w * 2048 + lane * 8;    // wave-uniform + lane*16B

    floatx4 acc[4][4] = {};

    for (int k0 = 0; k0 < K; k0 += 64) {
        #pragma unroll
        for (int i = 0; i < 4; i++)
            gl2lds16(Az + (aRow + i * 8) * (long)K + k0 + swz,
                     &As[ldsOff + i * 512]);
        #pragma unroll
        for (int j = 0; j < 4; j++)
            gl2lds16(Bz + (bRow + j * 8) * (long)K + k0 + swz,
                     &Bs[ldsOff + j * 512]);
        __syncthreads();
        #pragma unroll
        for (int kk = 0; kk < 2; kk++) {
            const int sw = ((kk * 4 + quad) ^ (l15 & 7)) * 8;
            short8 af[4], bfv[4];
            #pragma unroll
            for (int t = 0; t < 4; t++)
                af[t] = *(const short8*)&As[(wr * 64 + t * 16 + l15) * 64 + sw];
            #pragma unroll
            for (int u = 0; u < 4; u++)
                bfv[u] = *(const short8*)&Bs[(wc * 64 + u * 16 + l15) * 64 + sw];
            #pragma unroll
            for (int t = 0; t < 4; t++)
                #pragma unroll
                for (int u = 0; u < 4; u++)
                    acc[t][u] = __builtin_amdgcn_mfma_f32_16x16x32_bf16(af[t], bfv[u], acc[t][u], 0, 0, 0);
        }
        __syncthreads();
    }

    #pragma unroll
    for (int u = 0; u < 4; u++) {
        int n = n_base + wc * 64 + u * 16 + l15;
        float scale = 1.f, bias = 0.f;
        if (sbz) { scale = sbz[n]; bias = sbz[sbN + n]; }
        #pragma unroll
        for (int t = 0; t < 4; t++) {
            int mrow = m_base + wr * 64 + t * 16 + quad * 4;
            #pragma unroll
            for (int r = 0; r < 4; r++) {
                float v = acc[t][u][r];
                v = v * scale + bias;
                if (relu) v = fmaxf(v, 0.f);
                Cz[(long)(mrow + r) * ldc + n] = f2b(v);
            }
        }
    }
}

// ---------------- gather + softmax: y_t[n][p][m3584] -> P_t[n][ab][ij] -----
// Grid x = 1024: blocks ab>=900 write zero rows (replaces the P memset);
// pad cols ij in [900,1024) written as zero by all blocks.
// dual=1: blockIdx.y encodes {branch(2) x batch(4)}; branch 0 = collect.
__global__ __launch_bounds__(256) void softmax_gather_k(const u16* __restrict__ y,
                                                        u16* __restrict__ P,
                                                        int collect, long yS2,
                                                        long pS2, int dual)
{
    const int ab = blockIdx.x;      // 0..1023
    int n;
    if (dual) {
        int br = blockIdx.y >> 2;
        n = blockIdx.y & 3;
        collect = (br == 0);
        y += (long)br * yS2;
        P += (long)br * pS2;
    } else {
        n = blockIdx.y;
    }
    const int t = threadIdx.x;
    u16* Prow = P + ((long)n * PP + ab) * PP;

    if (ab >= SP) {                 // pad rows -> exact zeros
        #pragma unroll
        for (int q = 0; q < 4; q++) Prow[t + q * 256] = 0;
        return;
    }

    const int a = ab / SW, b = ab - a * SW;
    __shared__ float red[4];

    float vals[4];
    float mx = -1e30f;
    #pragma unroll
    for (int q = 0; q < 4; q++) {
        int ij = t + q * 256;
        float v = -1e30f;
        if (ij < SP) {
            int i = ij / SW, j = ij - (ij / SW) * SW;
            long idx;
            if (collect) idx = ((long)n * PP + ab) * MMpad + (i - a + 29) * 59 + (j - b + 29);
            else         idx = ((long)n * PP + ij) * MMpad + (a - i + 29) * 59 + (b - j + 29);
            v = b2f(y[idx]);
        }
        vals[q] = v;
        mx = fmaxf(mx, v);
    }
    #pragma unroll
    for (int off = 32; off; off >>= 1) mx = fmaxf(mx, __shfl_xor(mx, off, 64));
    if ((t & 63) == 0) red[t >> 6] = mx;
    __syncthreads();
    mx = fmaxf(fmaxf(red[0], red[1]), fmaxf(red[2], red[3]));
    __syncthreads();

    float s = 0.f;
    #pragma unroll
    for (int q = 0; q < 4; q++) {
        if (vals[q] > -1e29f) { vals[q] = expf(vals[q] - mx); s += vals[q]; }
        else vals[q] = 0.f;
    }
    #pragma unroll
    for (int off = 32; off; off >>= 1) s += __shfl_xor(s, off, 64);
    if ((t & 63) == 0) red[t >> 6] = s;
    __syncthreads();
    s = red[0] + red[1] + red[2] + red[3];
    float inv = 1.f / s;
    #pragma unroll
    for (int q = 0; q < 4; q++) {
        int ij = t + q * 256;
        Prow[ij] = f2b(vals[q] * inv);   // vals==0 for pad cols -> writes 0
    }
}

// ---------------- 2x upsample from xp_t[n][p][c], write out 2nd half --------
__global__ __launch_bounds__(256) void upsample_k(const u16* __restrict__ xp,
                                                  void* __restrict__ out,
                                                  const int* __restrict__ flag)
{
    __shared__ u16 ls[2][30][66];
    const int f = *flag;
    const int o0 = blockIdx.x * 64;
    const int y  = blockIdx.y;          // 0..58
    const int n  = blockIdx.z;
    const int tid = threadIdx.x;
    const int i = y >> 1;
    const int i1 = (i + 1 < 30) ? i + 1 : 29;
    const int c = tid & 63;
    for (int row = tid >> 6; row < 60; row += 4) {
        int r = row / 30, j = row - 30 * (row / 30);
        int pr = (r == 0) ? i : i1;
        ls[r][j][c] = xp[((long)n * PP + pr * 30 + j) * CIN + o0 + c];
    }
    __syncthreads();
    const int xcol = tid & 63;
    const int oi = tid >> 6;
    if (xcol < 59) {
        int j = xcol >> 1;
        bool xe = !(xcol & 1), ye = !(y & 1);
        for (int oo = oi; oo < 64; oo += 4) {
            float v00 = b2f(ls[0][j][oo]);
            float v;
            if (ye && xe)      v = v00;
            else if (ye)       v = 0.5f * (v00 + b2f(ls[0][j + 1][oo]));
            else if (xe)       v = 0.5f * (v00 + b2f(ls[1][j][oo]));
            else               v = 0.25f * (v00 + b2f(ls[0][j + 1][oo])
                                          + b2f(ls[1][j][oo]) + b2f(ls[1][j + 1][oo]));
            long oidx = ((long)n * (2 * CIN) + CIN + o0 + oo) * HW + (long)y * 59 + xcol;
            if (f) ((float*)out)[oidx] = v;
            else   ((u16*)out)[oidx] = f2b(v);
        }
    }
}

// ---------------- launch ----------------
extern "C" void kernel_launch(void* const* d_in, const int* in_sizes, int n_in,
                              void* d_out, int out_size, void* d_ws, size_t ws_size,
                              hipStream_t stream)
{
    const void* x    = d_in[0];
    const void* rw   = d_in[1];
    const void* rbn  = d_in[2];
    const void* a1w  = d_in[3];
    const void* abn  = d_in[4];
    const void* a2w  = d_in[5];
    const void* rpw  = d_in[6];
    const void* rpbn = d_in[7];
    const void* ap1w = d_in[8];
    const void* apbn = d_in[9];
    const void* ap2w = d_in[10];
    const void* pjw  = d_in[11];
    const void* pjbn = d_in[12];

    const long sMid = (long)PP * MID;      // 524288 u16
    const long sO   = (long)MID * PP;      // 524288 u16
    const long sPPl = (long)PP * PP;       // 1048576 u16
    const long sMM  = (long)PP * MMpad;    // 3670016 u16

    // big layout needs 2x y_t: guard on ws_size, fall back to serial branches
    const int bigWs = (ws_size >= 134251776UL) ? 1 : 0;

    char* W = (char*)d_ws;
    int* flag    = (int*)(W + 0);
    u16* rw_b    = (u16*)(W + 1024);          // 512x2048
    u16* rpw_b   = (u16*)(W + 2098176);       // 512x2048 (contiguous)
    u16* a1w_b   = (u16*)(W + 4195328);       // 512x512
    u16* ap1w_b  = (u16*)(W + 4719616);       // contiguous
    u16* a2w_b   = (u16*)(W + 5243904);       // 3584x512 (pad rows garbage)
    u16* ap2w_b  = (u16*)(W + 8913920);       // contiguous (+1835008 u16)
    u16* pjw_b   = (u16*)(W + 12583936);      // 2048x1024
    float* sbG1  = (float*)(W + 16778240);    // [s_c|b_c][s_d|b_d] 2048 f
    float* sbG2  = (float*)(W + 16786432);
    float* pj_sb = (float*)(W + 16794624);    // [s(2048)|b(2048)]
    u16* x_small_t = (u16*)(W + 16811264);    // 4x1024x2048 (reused: h1, xp_t)
    u16* xc_t      = (u16*)(W + 33588480);    // 4x1024x512
    u16* xc_o      = (u16*)(W + 41977088);    // 4x512x1024 (+xd_o contiguous)
    u16* y_t       = (u16*)(W + 50365696);    // 4x1024x3584 (x2 if bigWs)
    u16* Pc        = bigWs ? (u16*)(W + 109085952) : (u16*)(W + 79725824);
    u16* Pd        = Pc + 4 * sPPl;           // contiguous
    u16* cat_t     = Pd + 4 * sPPl;           // contiguous
    u16* h1        = x_small_t;               // 2 x [4096][512] after G1
    u16* xp_t      = x_small_t;               // [4096][2048] after agg

    WArgs wa;
    wa.src[0] = rw;   wa.dst[0] = rw_b;   wa.n[0] = 1048576;
    wa.src[1] = rpw;  wa.dst[1] = rpw_b;  wa.n[1] = 1048576;
    wa.src[2] = a1w;  wa.dst[2] = a1w_b;  wa.n[2] = 262144;
    wa.src[3] = ap1w; wa.dst[3] = ap1w_b; wa.n[3] = 262144;
    wa.src[4] = a2w;  wa.dst[4] = a2w_b;  wa.n[4] = 1782272;
    wa.src[5] = ap2w; wa.dst[5] = ap2w_b; wa.n[5] = 1782272;
    wa.src[6] = pjw;  wa.dst[6] = pjw_b;  wa.n[6] = 2097152;

    BArgs ba;
    ba.src[0] = rbn;  ba.dst[0] = sbG1;        ba.C[0] = 512;  ba.sbN[0] = 512;
    ba.src[1] = rpbn; ba.dst[1] = sbG1 + 1024; ba.C[1] = 512;  ba.sbN[1] = 512;
    ba.src[2] = abn;  ba.dst[2] = sbG2;        ba.C[2] = 512;  ba.sbN[2] = 512;
    ba.src[3] = apbn; ba.dst[3] = sbG2 + 1024; ba.C[3] = 512;  ba.sbN[3] = 512;
    ba.src[4] = pjbn; ba.dst[4] = pj_sb;       ba.C[4] = 2048; ba.sbN[4] = 2048;

    // 1) probe (tiny), 2) prep: subsampleT + copy + weight cvt + BN prep
    hipLaunchKernelGGL(probe_k, dim3(1), dim3(256), 0, stream, (const u16*)x, flag);
    hipLaunchKernelGGL(prep_all, dim3(9256), dim3(256), 0, stream,
                       x, d_out, x_small_t, wa, ba, flag);

    // 3) G1: [xc_t|xd_t] = relu(bn(x_small @ {rw,rpw}^T)); z=branch
    hipLaunchKernelGGL(mfma_gemm, dim3(4, 32, 2), dim3(256), 0, stream,
                       x_small_t, 0L, 0L,
                       rw_b, 0L, 1048576L,
                       xc_t, 0L, 4 * sMid, 1, 2,
                       MID, CIN, 0, sbG1, 512, 1024L, 1,
                       nullptr, nullptr);
    // 4) G2 + fused transposes: z 0..1 GEMM, z 2..9 transpose (8 x 128 blk)
    hipLaunchKernelGGL(mfma_gemm, dim3(4, 32, 10), dim3(256), 0, stream,
                       xc_t, 0L, 4 * sMid,
                       a1w_b, 0L, 262144L,
                       h1, 0L, 4 * sMid, 1, 2,
                       MID, MID, 0, sbG2, 512, 1024L, 1,
                       xc_t, xc_o);

    if (bigWs) {
        // 5) G3 both branches, band-trimmed (gridx 18 covers any band)
        hipLaunchKernelGGL(mfma_gemm, dim3(18, 32, 2), dim3(256), 0, stream,
                           h1, 0L, 4 * sMid,
                           a2w_b, 0L, 1835008L,
                           y_t, 0L, 4 * sMM, 1, 2,
                           MMpad, MID, 1, (const float*)nullptr, 0, 0L, 0,
                           nullptr, nullptr);
        // 6) softmax both branches; self-zeroes P pad rows/cols
        hipLaunchKernelGGL(softmax_gather_k, dim3(1024, 8), dim3(256), 0, stream,
                           y_t, Pc, 0, 4 * sMM, 4 * sPPl, 1);
    } else {
        hipLaunchKernelGGL(mfma_gemm, dim3(18, 32, 1), dim3(256), 0, stream,
                           h1, 0L, 0L, a2w_b, 0L, 0L, y_t, 0L, 0L, 1, 1,
                           MMpad, MID, 1, (const float*)nullptr, 0, 0L, 0,
                           nullptr, nullptr);
        hipLaunchKernelGGL(softmax_gather_k, dim3(1024, 4), dim3(256), 0, stream,
                           y_t, Pc, 1, 0L, 0L, 0);
        hipLaunchKernelGGL(mfma_gemm, dim3(18, 32, 1), dim3(256), 0, stream,
                           h1 + 4 * sMid, 0L, 0L, ap2w_b, 0L, 0L, y_t, 0L, 0L, 1, 1,
                           MMpad, MID, 1, (const float*)nullptr, 0, 0L, 0,
                           nullptr, nullptr);
        hipLaunchKernelGGL(softmax_gather_k, dim3(1024, 4), dim3(256), 0, stream,
                           y_t, Pd, 0, 0L, 0L, 0);
    }

    // 7) agg: cat_t[:, :512] = Pc @ xc_o^T ; cat_t[:, 512:] = Pd @ xd_o^T
    //    K must equal the buffers' row stride (PP) — R5's 960 trim broke this.
    hipLaunchKernelGGL(mfma_gemm, dim3(4, 8, 8), dim3(256), 0, stream,
                       Pc, sPPl, 4 * sPPl,
                       xc_o, sO, 4 * sO,
                       cat_t, sPPl, 512L, 4, 8,
                       PP, PP, 0, (const float*)nullptr, 0, 0L, 0,
                       nullptr, nullptr);
    // 8) projection: xp_t = relu(bn(cat_t @ pjw^T)); M=4096
    hipLaunchKernelGGL(mfma_gemm, dim3(16, 32, 1), dim3(256), 0, stream,
                       cat_t, 0L, 0L,
                       pjw_b, 0L, 0L,
                       xp_t, 0L, 0L, 1, 1,
                       CIN, PP, 0, pj_sb, 2048, 0L, 1,
                       nullptr, nullptr);
    // 9) upsample
    hipLaunchKernelGGL(upsample_k, dim3(32, 59, 4), dim3(256), 0, stream,
                       xp_t, d_out, flag);
}